// Round 1
// baseline (397.523 us; speedup 1.0000x reference)
//
#include <hip/hip_runtime.h>
#include <cstdint>
#include <cstddef>

// CRF loss forward: out[b] = log_norm(b) - target_score(b)
// B=512, N=1024, K=64.
//
// Strategy: one wave (64 lanes) per batch row. Lane j owns alpha_j in
// exp-domain: z_j = exp(alpha_j - M0 - S*ln2), S integer (exact pow2 rescale).
// Per step: z_new_j = (sum_i z_i * E_ij) * exp(emit_j) * 2^-s
// with E_ij = exp(trans[i][j]) held in 64 VGPRs (column j per lane).
// z broadcast via double-buffered LDS (uniform-address reads = HW broadcast).

constexpr int Nn = 1024;
constexpr int Kk = 64;

__global__ __launch_bounds__(64, 1) void crf_fwd(
    const float* __restrict__ y_pred,   // [B,N,K]
    const float* __restrict__ trans,    // [K,K]
    const int*   __restrict__ y_true,   // [B,N]
    float* __restrict__ out)            // [B]
{
    const int b = blockIdx.x;
    const int j = threadIdx.x;  // 0..63

    __shared__ float zbuf[2][Kk];

    const float LOG2E = 1.4426950408889634f;
    const float LN2   = 0.6931471805599453f;

    // E' column j: e[i] = exp(trans[i][j]); coalesced loads (stride K across i).
    float e[Kk];
#pragma unroll
    for (int i = 0; i < Kk; ++i) {
        e[i] = exp2f(trans[i * Kk + j] * LOG2E);
    }

    const float* yp  = y_pred + (size_t)b * Nn * Kk;
    const int*   ytb = y_true + (size_t)b * Nn;

    // ---- t = 0 ----
    float emit0 = yp[j];
    bool  m0    = (bool)__all(emit0 > -1000000.0f);
    float a0    = m0 ? emit0 : 0.0f;
    float M0    = __uint_as_float(__builtin_amdgcn_readfirstlane(__float_as_uint(a0)));
    float z     = exp2f((a0 - M0) * LOG2E);

    int   yt0   = ytb[0];
    float pacc  = (m0 && j == yt0) ? emit0 : 0.0f;  // point-score accumulator (per lane)
    float tacc  = 0.0f;                              // trans-pair accumulator (uniform)
    int   S     = 0;                                 // pow2 rescale accumulator (exact)
    int   yt_prev = yt0;
    bool  m_prev  = m0;

    // prefetch t=1
    float emit_next = yp[Kk + j];
    int   yt_next   = ytb[1];

    for (int t = 1; t < Nn; ++t) {
        float emit = emit_next;
        int   yt   = yt_next;
        if (t + 1 < Nn) {
            emit_next = yp[(size_t)(t + 1) * Kk + j];
            yt_next   = ytb[t + 1];
        }
        bool m = (bool)__all(emit > -1000000.0f);

        // lagged pow2 rescale: exponent of lane-0's current z (exact, cheap)
        uint32_t zb0 = __builtin_amdgcn_readfirstlane(__float_as_uint(z));
        int s = (int)((zb0 >> 23) & 0xFF) - 127;

        float pe = exp2f(emit * LOG2E);                 // exp(emit_j), off critical path
        float tv = trans[yt_prev * Kk + yt];            // uniform, L1-cached

        // broadcast z through LDS (double-buffered: one sync per step)
        float* zcur = zbuf[t & 1];
        zcur[j] = z;
        __syncthreads();

        float acc0 = 0.f, acc1 = 0.f, acc2 = 0.f, acc3 = 0.f;
#pragma unroll
        for (int i = 0; i < Kk; i += 4) {
            float4 zi = *reinterpret_cast<const float4*>(zcur + i);  // uniform addr -> broadcast
            acc0 = fmaf(zi.x, e[i + 0], acc0);
            acc1 = fmaf(zi.y, e[i + 1], acc1);
            acc2 = fmaf(zi.z, e[i + 2], acc2);
            acc3 = fmaf(zi.w, e[i + 3], acc3);
        }
        float dot = (acc0 + acc1) + (acc2 + acc3);

        float znew = ldexpf(dot * pe, -s);

        z     = m ? znew : z;
        S    += m ? s : 0;
        pacc += (m && j == yt) ? emit : 0.0f;
        tacc += (m && m_prev) ? tv : 0.0f;

        yt_prev = yt;
        m_prev  = m;
    }

    // epilogue: wave reductions
    float sz = z;
    float sp = pacc;
#pragma unroll
    for (int off = 32; off; off >>= 1) {
        sz += __shfl_xor(sz, off);
        sp += __shfl_xor(sp, off);
    }

    if (j == 0) {
        float log_norm = logf(sz) + (float)S * LN2 + M0;
        out[b] = log_norm - (sp + tacc);
    }
}

extern "C" void kernel_launch(void* const* d_in, const int* in_sizes, int n_in,
                              void* d_out, int out_size, void* d_ws, size_t ws_size,
                              hipStream_t stream) {
    const float* y_pred = (const float*)d_in[0];
    const float* trans  = (const float*)d_in[1];
    const int*   y_true = (const int*)d_in[2];
    float* out = (float*)d_out;

    const int B = 512;
    crf_fwd<<<B, Kk, 0, stream>>>(y_pred, trans, y_true, out);
}

// Round 2
// 307.862 us; speedup vs baseline: 1.2912x; 1.2912x over previous
//
#include <hip/hip_runtime.h>
#include <cstdint>
#include <cstddef>

// CRF loss forward: out[b] = log_norm(b) - target_score(b)
// B=512, N=1024, K=64. One wave (64 lanes) per batch row.
//
// Lane j owns alpha_j in exp-domain: z_j = exp(alpha_j - M0 - S*ln2).
// Per step: z_new_j = (sum_i z_i * E_ij) * exp(emit_j) * 2^-s,
// E_ij = exp(trans[i][j]) held in VGPRs (packed v2f pairs).
//
// Key latency fixes vs R1:
//  - NO __syncthreads in the loop (it drains vmcnt(0) -> every step paid
//    full HBM latency). Single-wave block => lgkmcnt(0) fence suffices
//    for the LDS write->read broadcast.
//  - 8-deep register ring prefetch of emit/y_true (static indices via
//    8x unroll), depth-2 ring for trans-pair values: no in-step
//    dependent global load.
//  - v_pk_fma_f32 dot (32 packed FMAs, 4 accumulator chains).

constexpr int Nn = 1024;
constexpr int Kk = 64;
constexpr int P  = 8;   // emit/yt prefetch depth (power of 2)

typedef float v2f __attribute__((ext_vector_type(2)));

#define LDS_FENCE() asm volatile("s_waitcnt lgkmcnt(0)" ::: "memory")

__global__ __launch_bounds__(64, 1) void crf_fwd(
    const float* __restrict__ y_pred,   // [B,N,K]
    const float* __restrict__ trans,    // [K,K]
    const int*   __restrict__ y_true,   // [B,N]
    float* __restrict__ out)            // [B]
{
    const int b = blockIdx.x;
    const int j = threadIdx.x;  // 0..63

    __shared__ float zbuf[2][Kk];

    const float LOG2E = 1.4426950408889634f;
    const float LN2   = 0.6931471805599453f;

    // E column j as packed pairs: e2[p] = {exp(trans[2p][j]), exp(trans[2p+1][j])}
    v2f e2[Kk / 2];
#pragma unroll
    for (int p = 0; p < Kk / 2; ++p) {
        float lo = exp2f(trans[(2 * p)     * Kk + j] * LOG2E);
        float hi = exp2f(trans[(2 * p + 1) * Kk + j] * LOG2E);
        e2[p] = (v2f){lo, hi};
    }

    const float* yp  = y_pred + (size_t)b * Nn * Kk;
    const int*   ytb = y_true + (size_t)b * Nn;

    // ---- t = 0 ----
    float emit0 = yp[j];
    bool  m0 = (bool)__all(emit0 > -1000000.0f);
    float a0 = m0 ? emit0 : 0.0f;
    float M0 = __uint_as_float(__builtin_amdgcn_readfirstlane(__float_as_uint(a0)));
    float z  = exp2f((a0 - M0) * LOG2E);

    int   yt0  = ytb[0];
    float pacc = (m0 && j == yt0) ? emit0 : 0.0f;  // point-score accumulator
    float tacc = 0.0f;                              // trans-pair accumulator
    int   S    = 0;                                 // pow2 rescale accumulator
    bool  m_prev = m0;

    // prefetch rings: emit/yt for steps 1..P, slot = step & (P-1)
    float ering[P];
    int   yring[P];
#pragma unroll
    for (int p = 1; p <= P; ++p) {
        ering[p & (P - 1)] = yp[(size_t)p * Kk + j];
        yring[p & (P - 1)] = ytb[p];
    }
    // tv ring (depth 2): tv for step t = trans[yt[t-1]*K + yt[t]], slot = t & 1
    float tvr[2];
    tvr[1] = trans[yt0      * Kk + yring[1]];   // step 1
    tvr[0] = trans[yring[1] * Kk + yring[2]];   // step 2

    auto STEP = [&](int t, int slot, int tslot) {
        float emit = ering[slot];
        int   yt   = yring[slot];
        // issue prefetch for step t+P into the just-freed slot
        int tt = t + P;
        tt = (tt > Nn - 1) ? (Nn - 1) : tt;
        ering[slot] = yp[(size_t)tt * Kk + j];
        yring[slot] = ytb[tt];

        bool m = (bool)__all(emit > -1000000.0f);

        // lagged pow2 rescale: exponent of lane-0's current z (exact)
        uint32_t zb0 = __builtin_amdgcn_readfirstlane(__float_as_uint(z));
        int s = (int)((zb0 >> 23) & 0xFF) - 127;

        float pe  = exp2f(emit * LOG2E);
        float tvv = tvr[tslot];
        // prefetch tv for step t+2 (same slot): trans[yt[t+1]][yt[t+2]]
        tvr[tslot] = trans[yring[(slot + 1) & (P - 1)] * Kk +
                           yring[(slot + 2) & (P - 1)]];

        // broadcast z through LDS (double-buffered); single-wave block =>
        // lgkmcnt(0) is a sufficient fence, does NOT drain vmcnt.
        float* zc = zbuf[t & 1];
        zc[j] = z;
        LDS_FENCE();

        v2f acc0 = {0.f, 0.f}, acc1 = {0.f, 0.f};
        v2f acc2 = {0.f, 0.f}, acc3 = {0.f, 0.f};
#pragma unroll
        for (int q = 0; q < 16; q += 2) {
            float4 za = *reinterpret_cast<const float4*>(zc + 4 * q);
            float4 zb = *reinterpret_cast<const float4*>(zc + 4 * q + 4);
            acc0 = __builtin_elementwise_fma((v2f){za.x, za.y}, e2[2 * q],     acc0);
            acc1 = __builtin_elementwise_fma((v2f){za.z, za.w}, e2[2 * q + 1], acc1);
            acc2 = __builtin_elementwise_fma((v2f){zb.x, zb.y}, e2[2 * q + 2], acc2);
            acc3 = __builtin_elementwise_fma((v2f){zb.z, zb.w}, e2[2 * q + 3], acc3);
        }
        v2f accS = (acc0 + acc1) + (acc2 + acc3);
        float dot = accS.x + accS.y;

        float znew = ldexpf(dot * pe, -s);
        z     = m ? znew : z;
        S    += m ? s : 0;
        pacc += (m && j == yt) ? emit : 0.0f;
        tacc += (m && m_prev) ? tvv : 0.0f;
        m_prev = m;
    };

    // main loop: 127 blocks of 8 (t = 1..1016), static ring indices
    for (int tb = 0; tb < 127; ++tb) {
        const int tbase = tb * 8;
#pragma unroll
        for (int u = 1; u <= 8; ++u) {
            STEP(tbase + u, u & 7, u & 1);
        }
    }
    // tail: t = 1017..1023 (fully unrolled, static indices)
#pragma unroll
    for (int t = 1017; t < Nn; ++t) {
        STEP(t, t & 7, t & 1);
    }

    // epilogue: wave reductions
    float sz = z;
    float sp = pacc;
#pragma unroll
    for (int off = 32; off; off >>= 1) {
        sz += __shfl_xor(sz, off);
        sp += __shfl_xor(sp, off);
    }

    if (j == 0) {
        float log_norm = logf(sz) + (float)S * LN2 + M0;
        out[b] = log_norm - (sp + tacc);
    }
}

extern "C" void kernel_launch(void* const* d_in, const int* in_sizes, int n_in,
                              void* d_out, int out_size, void* d_ws, size_t ws_size,
                              hipStream_t stream) {
    const float* y_pred = (const float*)d_in[0];
    const float* trans  = (const float*)d_in[1];
    const int*   y_true = (const int*)d_in[2];
    float* out = (float*)d_out;

    const int B = 512;
    crf_fwd<<<B, Kk, 0, stream>>>(y_pred, trans, y_true, out);
}